// Round 1
// baseline (674.723 us; speedup 1.0000x reference)
//
#include <hip/hip_runtime.h>
#include <math.h>

#define T_TOK 4096
#define D_DIM 1024
#define H_DIM 2048
#define NE 8
#define EPSF 1e-8f

typedef __attribute__((ext_vector_type(8))) short bf16x8;
typedef __attribute__((ext_vector_type(4))) float f32x4;

__device__ __forceinline__ unsigned short f2bf(float f) {
  unsigned u = __float_as_uint(f);
  u += 0x7fffu + ((u >> 16) & 1u);
  return (unsigned short)(u >> 16);
}

__device__ __forceinline__ void gload_lds16(const void* g, void* l) {
  __builtin_amdgcn_global_load_lds(
      (const __attribute__((address_space(1))) unsigned int*)g,
      (__attribute__((address_space(3))) unsigned int*)l, 16, 0, 0);
}

// ---------------------------------------------------------------- small init
__global__ void zero_small_kernel(unsigned* cnt, unsigned* usage) {
  if (threadIdx.x < NE) { cnt[threadIdx.x] = 0u; usage[threadIdx.x] = 0u; }
}

// ---------------------------------------------------------------- cast x -> bf16
__global__ void cast_x_kernel(const float* __restrict__ x, unsigned short* __restrict__ xb) {
  int id = blockIdx.x * blockDim.x + threadIdx.x;  // one uint4 (8 bf16) per thread
  const float4* src = (const float4*)x;
  float4 a = src[id * 2], b = src[id * 2 + 1];
  union { unsigned short u[8]; uint4 v; } o;
  o.u[0] = f2bf(a.x); o.u[1] = f2bf(a.y); o.u[2] = f2bf(a.z); o.u[3] = f2bf(a.w);
  o.u[4] = f2bf(b.x); o.u[5] = f2bf(b.y); o.u[6] = f2bf(b.z); o.u[7] = f2bf(b.w);
  ((uint4*)xb)[id] = o.v;
}

// ---------------------------------------------------------------- transpose + cast weights
// src: (R x C) f32, dst: (C x R) bf16.  z-block 0..7 -> expert matrices, 8 -> shared matrix.
template <int R, int C>
__global__ void transpose_cast_kernel(const float* __restrict__ srcE, const float* __restrict__ srcS,
                                      unsigned short* __restrict__ dstE, unsigned short* __restrict__ dstS) {
  __shared__ float tile[64][65];
  int m = blockIdx.z;
  const float* src = (m < NE) ? srcE + (size_t)m * R * C : srcS;
  unsigned short* dst = (m < NE) ? dstE + (size_t)m * R * C : dstS;
  int r0 = blockIdx.y * 64, c0 = blockIdx.x * 64;
  int tid = threadIdx.x;
#pragma unroll
  for (int k = 0; k < 4; ++k) {
    int id = tid + k * 256;
    int row = id >> 4, c4 = (id & 15) * 4;
    float4 v = *(const float4*)(src + (size_t)(r0 + row) * C + c0 + c4);
    tile[row][c4 + 0] = v.x; tile[row][c4 + 1] = v.y;
    tile[row][c4 + 2] = v.z; tile[row][c4 + 3] = v.w;
  }
  __syncthreads();
#pragma unroll
  for (int k = 0; k < 2; ++k) {
    int id = tid + k * 256;
    int oc = id >> 3, rbase = (id & 7) * 8;
    uint4 w;
    unsigned* wp = (unsigned*)&w;
#pragma unroll
    for (int j = 0; j < 4; ++j) {
      unsigned lo = f2bf(tile[rbase + 2 * j][oc]);
      unsigned hi = f2bf(tile[rbase + 2 * j + 1][oc]);
      wp[j] = lo | (hi << 16);
    }
    *(uint4*)(dst + (size_t)(c0 + oc) * R + r0 + rbase) = w;
  }
}

// ---------------------------------------------------------------- gating: logits, softmax, top-2, usage
__global__ void gate_kernel(const float* __restrict__ x, const float* __restrict__ gW,
                            const float* __restrict__ gb, const float* __restrict__ gtemp,
                            float* __restrict__ scores, int* __restrict__ idx,
                            unsigned* __restrict__ usage) {
  int wave = threadIdx.x >> 6, lane = threadIdx.x & 63;
  int t = blockIdx.x * 4 + wave;
  float part[NE];
#pragma unroll
  for (int e = 0; e < NE; ++e) part[e] = 0.f;
  const float* xr = x + (size_t)t * D_DIM;
  for (int d = lane; d < D_DIM; d += 64) {
    float xv = xr[d];
    const float* g = gW + (size_t)d * NE;
#pragma unroll
    for (int e = 0; e < NE; ++e) part[e] += xv * g[e];
  }
#pragma unroll
  for (int e = 0; e < NE; ++e) {
    float v = part[e];
    for (int off = 32; off; off >>= 1) v += __shfl_xor(v, off);
    part[e] = v;
  }
  float temp = gtemp[0];
  float mx = -1e30f;
#pragma unroll
  for (int e = 0; e < NE; ++e) { part[e] = (part[e] + gb[e]) / temp; mx = fmaxf(mx, part[e]); }
  float s = 0.f;
#pragma unroll
  for (int e = 0; e < NE; ++e) { part[e] = expf(part[e] - mx); s += part[e]; }
  float inv = 1.0f / s;
#pragma unroll
  for (int e = 0; e < NE; ++e) part[e] *= inv;
  if (lane == 0) {
    float4* sp = (float4*)(scores + (size_t)t * NE);
    sp[0] = make_float4(part[0], part[1], part[2], part[3]);
    sp[1] = make_float4(part[4], part[5], part[6], part[7]);
    int i0 = 0; float b0 = part[0];
#pragma unroll
    for (int e = 1; e < NE; ++e) if (part[e] > b0) { b0 = part[e]; i0 = e; }
    int i1 = -1; float b1 = -1e30f;
#pragma unroll
    for (int e = 0; e < NE; ++e) if (e != i0 && part[e] > b1) { b1 = part[e]; i1 = e; }
    idx[t * 2] = i0; idx[t * 2 + 1] = i1;
    atomicAdd(&usage[i0], 1u);
  }
}

// ---------------------------------------------------------------- EM (5 iters) + KL loss
__global__ void em_loss_kernel(const float* __restrict__ scores, const unsigned* __restrict__ usage,
                               float* __restrict__ p_out, float* __restrict__ loss_out) {
  __shared__ float p_sh[NE];
  __shared__ float cw[16][NE];
  __shared__ float counts_sh[NE];
  int tid = threadIdx.x, wave = tid >> 6, lane = tid & 63;
  float s[4][NE];
#pragma unroll
  for (int rr = 0; rr < 4; ++rr) {
    int row = tid + rr * 1024;
    const float4* sp = (const float4*)(scores + (size_t)row * NE);
    float4 a = sp[0], b = sp[1];
    s[rr][0] = a.x; s[rr][1] = a.y; s[rr][2] = a.z; s[rr][3] = a.w;
    s[rr][4] = b.x; s[rr][5] = b.y; s[rr][6] = b.z; s[rr][7] = b.w;
  }
  if (tid < NE) p_sh[tid] = 1.0f / NE;
  __syncthreads();
  for (int it = 0; it < 5; ++it) {
    float p[NE];
#pragma unroll
    for (int e = 0; e < NE; ++e) p[e] = p_sh[e];
    float c[NE];
#pragma unroll
    for (int e = 0; e < NE; ++e) c[e] = 0.f;
#pragma unroll
    for (int rr = 0; rr < 4; ++rr) {
      float denom = 0.f;
#pragma unroll
      for (int e = 0; e < NE; ++e) denom += s[rr][e] * p[e];
      float inv = 1.0f / (denom + EPSF);
#pragma unroll
      for (int e = 0; e < NE; ++e) c[e] += s[rr][e] * p[e] * inv;
    }
#pragma unroll
    for (int e = 0; e < NE; ++e) {
      float v = c[e];
      for (int off = 32; off; off >>= 1) v += __shfl_xor(v, off);
      c[e] = v;
    }
    if (lane == 0) {
#pragma unroll
      for (int e = 0; e < NE; ++e) cw[wave][e] = c[e];
    }
    __syncthreads();
    if (tid < NE) {
      float tot = 0.f;
#pragma unroll
      for (int w = 0; w < 16; ++w) tot += cw[w][tid];
      counts_sh[tid] = tot;
    }
    __syncthreads();
    if (tid < NE) {
      float total = 0.f;
#pragma unroll
      for (int e = 0; e < NE; ++e) total += counts_sh[e];
      p_sh[tid] = counts_sh[tid] / (total + EPSF);
    }
    __syncthreads();
  }
  if (tid < NE) p_out[tid] = p_sh[tid];
  if (tid == 0) {
    float actual[NE]; float norm = 0.f;
#pragma unroll
    for (int e = 0; e < NE; ++e) { actual[e] = (float)usage[e] / (float)T_TOK + EPSF; norm += actual[e]; }
    float u = 1.0f / NE;
    float kl = 0.f;
#pragma unroll
    for (int e = 0; e < NE; ++e) kl += u * (logf(u) - logf(actual[e] / norm));
    loss_out[0] = 0.1f * kl;
  }
}

// ---------------------------------------------------------------- scatter tokens to expert lists
__global__ void scatter_kernel(const int* __restrict__ idx, unsigned* __restrict__ cnt,
                               int* __restrict__ perm) {
  int t = blockIdx.x * blockDim.x + threadIdx.x;
#pragma unroll
  for (int k = 0; k < 2; ++k) {
    int e = idx[t * 2 + k];
    unsigned pos = atomicAdd(&cnt[e], 1u);
    perm[(size_t)e * T_TOK + pos] = t * 2 + k;
  }
}

// ---------------------------------------------------------------- gathered bf16 MFMA GEMM
// MODE1 (stage 1): A-row = token id (perm>>1), out = Hbuf bf16 (relu(acc+bias))
// MODE2 (stage 2): A-row = slot id (perm),    out = ebuf f32  (acc+bias)
// expert index 8 = shared path (identity routing, rows 2T..3T-1).
template <int KDIM, int NDIM, bool RELU, bool MODE1>
__global__ __launch_bounds__(256) void gemm_kernel(
    const unsigned short* __restrict__ A, const unsigned short* __restrict__ WE,
    const unsigned short* __restrict__ WS, const float* __restrict__ biasE,
    const float* __restrict__ biasS, const int* __restrict__ perm,
    const unsigned* __restrict__ cnt, void* __restrict__ outp) {
  constexpr int BM = 128, BN = 128, BK = 64;
  constexpr int MT = T_TOK / BM;  // 32
  int e = blockIdx.x / MT, mt = blockIdx.x % MT;
  int m0 = mt * BM;
  int cnt_e = (e == NE) ? T_TOK : (int)cnt[e];
  if (m0 >= cnt_e) return;
  int n0 = blockIdx.y * BN;
  const unsigned short* Bmat = (e == NE) ? WS : WE + (size_t)e * KDIM * NDIM;
  const float* bias = (e == NE) ? biasS : biasE + (size_t)e * NDIM;

  __shared__ unsigned short As[BM * BK];
  __shared__ unsigned short Bs[BN * BK];

  int tid = threadIdx.x, wave = tid >> 6, lane = tid & 63;
  int wm = wave >> 1, wn = wave & 1;
  int lrow = lane >> 3;            // row within 8-row staging chunk
  int lcol = (lane & 7) * 8;       // bf16 element offset within row

  int asrc[4];
#pragma unroll
  for (int c = 0; c < 4; ++c) {
    int row = wave * 32 + c * 8 + lrow;
    int rr = m0 + row;
    if (rr > cnt_e - 1) rr = cnt_e - 1;
    if (e == NE) {
      asrc[c] = MODE1 ? rr : (2 * T_TOK + rr);
    } else {
      int v = perm[(size_t)e * T_TOK + rr];
      asrc[c] = MODE1 ? (v >> 1) : v;
    }
  }

  f32x4 acc[4][4];
#pragma unroll
  for (int i = 0; i < 4; ++i)
#pragma unroll
    for (int j = 0; j < 4; ++j) acc[i][j] = (f32x4){0.f, 0.f, 0.f, 0.f};

  for (int k0 = 0; k0 < KDIM; k0 += BK) {
#pragma unroll
    for (int c = 0; c < 4; ++c) {
      const unsigned short* g = A + (size_t)asrc[c] * KDIM + k0 + lcol;
      gload_lds16(g, &As[(wave * 32 + c * 8) * BK]);
    }
#pragma unroll
    for (int c = 0; c < 4; ++c) {
      int nrow = wave * 32 + c * 8 + lrow;
      const unsigned short* g = Bmat + (size_t)(n0 + nrow) * KDIM + k0 + lcol;
      gload_lds16(g, &Bs[(wave * 32 + c * 8) * BK]);
    }
    __syncthreads();
#pragma unroll
    for (int kk = 0; kk < BK; kk += 32) {
      bf16x8 af[4], bfr[4];
#pragma unroll
      for (int i = 0; i < 4; ++i)
        af[i] = *(const bf16x8*)&As[(wm * 64 + i * 16 + (lane & 15)) * BK + kk + (lane >> 4) * 8];
#pragma unroll
      for (int j = 0; j < 4; ++j)
        bfr[j] = *(const bf16x8*)&Bs[(wn * 64 + j * 16 + (lane & 15)) * BK + kk + (lane >> 4) * 8];
#pragma unroll
      for (int i = 0; i < 4; ++i)
#pragma unroll
        for (int j = 0; j < 4; ++j)
          acc[i][j] = __builtin_amdgcn_mfma_f32_16x16x32_bf16(af[i], bfr[j], acc[i][j], 0, 0, 0);
    }
    __syncthreads();
  }

#pragma unroll
  for (int i = 0; i < 4; ++i) {
#pragma unroll
    for (int q = 0; q < 4; ++q) {
      int rt = wm * 64 + i * 16 + (lane >> 4) * 4 + q;
      if (m0 + rt >= cnt_e) continue;
      int r;
      if (e == NE) r = 2 * T_TOK + m0 + rt;
      else r = perm[(size_t)e * T_TOK + m0 + rt];
#pragma unroll
      for (int j = 0; j < 4; ++j) {
        int col = n0 + wn * 64 + j * 16 + (lane & 15);
        float val = acc[i][j][q] + bias[col];
        if (RELU) val = fmaxf(val, 0.f);
        if (MODE1)
          ((unsigned short*)outp)[(size_t)r * NDIM + col] = f2bf(val);
        else
          ((float*)outp)[(size_t)r * NDIM + col] = val;
      }
    }
  }
}

// ---------------------------------------------------------------- combine
__global__ void combine_kernel(const float* __restrict__ ebuf, const float* __restrict__ scores,
                               const float* __restrict__ p, const int* __restrict__ idx,
                               float* __restrict__ out) {
  int gid = blockIdx.x * blockDim.x + threadIdx.x;  // one float4 per thread
  int t = gid >> 8;                                 // 256 float4 per 1024-wide row
  int d4 = gid & 255;
  int e0 = idx[t * 2], e1 = idx[t * 2 + 1];
  float w0 = scores[(size_t)t * NE + e0] * p[e0];
  float w1 = scores[(size_t)t * NE + e1] * p[e1];
  const float4* r0 = (const float4*)(ebuf + (size_t)(t * 2) * D_DIM);
  const float4* r1 = (const float4*)(ebuf + (size_t)(t * 2 + 1) * D_DIM);
  const float4* rs = (const float4*)(ebuf + (size_t)(2 * T_TOK + t) * D_DIM);
  float4 a = r0[d4], b = r1[d4], c = rs[d4];
  float4 o;
  o.x = w0 * a.x + w1 * b.x + 0.1f * c.x;
  o.y = w0 * a.y + w1 * b.y + 0.1f * c.y;
  o.z = w0 * a.z + w1 * b.z + 0.1f * c.z;
  o.w = w0 * a.w + w1 * b.w + 0.1f * c.w;
  ((float4*)out)[gid] = o;
}

// ---------------------------------------------------------------- launch
extern "C" void kernel_launch(void* const* d_in, const int* in_sizes, int n_in,
                              void* d_out, int out_size, void* d_ws, size_t ws_size,
                              hipStream_t stream) {
  const float* x     = (const float*)d_in[0];
  const float* gW    = (const float*)d_in[1];
  const float* gb    = (const float*)d_in[2];
  const float* gtemp = (const float*)d_in[3];
  const float* W1    = (const float*)d_in[4];
  const float* b1    = (const float*)d_in[5];
  const float* W2    = (const float*)d_in[6];
  const float* b2    = (const float*)d_in[7];
  const float* sW1   = (const float*)d_in[8];
  const float* sb1   = (const float*)d_in[9];
  const float* sW2   = (const float*)d_in[10];
  const float* sb2   = (const float*)d_in[11];
  float* out = (float*)d_out;

  char* ws = (char*)d_ws;
  size_t off = 0;
  auto take = [&](size_t b) { char* ptr = ws + off; off += (b + 255) & ~(size_t)255; return ptr; };
  unsigned short* xb   = (unsigned short*)take((size_t)T_TOK * D_DIM * 2);
  unsigned short* W1t  = (unsigned short*)take((size_t)NE * H_DIM * D_DIM * 2);
  unsigned short* sW1t = (unsigned short*)take((size_t)H_DIM * D_DIM * 2);
  unsigned short* W2t  = (unsigned short*)take((size_t)NE * D_DIM * H_DIM * 2);
  unsigned short* sW2t = (unsigned short*)take((size_t)D_DIM * H_DIM * 2);
  unsigned short* Hbuf = (unsigned short*)take((size_t)3 * T_TOK * H_DIM * 2);
  float* ebuf          = (float*)take((size_t)3 * T_TOK * D_DIM * 4);
  float* scores        = (float*)take((size_t)T_TOK * NE * 4);
  int* idx             = (int*)take((size_t)T_TOK * 2 * 4);
  int* perm            = (int*)take((size_t)NE * T_TOK * 4);
  unsigned* cnt        = (unsigned*)take(256);
  unsigned* usage      = (unsigned*)take(256);
  float* pbuf          = (float*)take(256);
  (void)n_in; (void)in_sizes; (void)out_size; (void)ws_size;

  zero_small_kernel<<<1, 64, 0, stream>>>(cnt, usage);
  cast_x_kernel<<<(T_TOK * D_DIM / 8) / 256, 256, 0, stream>>>(x, xb);
  transpose_cast_kernel<D_DIM, H_DIM><<<dim3(H_DIM / 64, D_DIM / 64, 9), 256, 0, stream>>>(W1, sW1, W1t, sW1t);
  transpose_cast_kernel<H_DIM, D_DIM><<<dim3(D_DIM / 64, H_DIM / 64, 9), 256, 0, stream>>>(W2, sW2, W2t, sW2t);
  gate_kernel<<<T_TOK / 4, 256, 0, stream>>>(x, gW, gb, gtemp, scores, idx, usage);
  em_loss_kernel<<<1, 1024, 0, stream>>>(scores, usage, pbuf, out + (size_t)T_TOK * D_DIM);
  scatter_kernel<<<T_TOK / 256, 256, 0, stream>>>(idx, cnt, perm);
  gemm_kernel<D_DIM, H_DIM, true, true><<<dim3(9 * 32, H_DIM / 128), 256, 0, stream>>>(
      xb, W1t, sW1t, b1, sb1, perm, cnt, (void*)Hbuf);
  gemm_kernel<H_DIM, D_DIM, false, false><<<dim3(9 * 32, D_DIM / 128), 256, 0, stream>>>(
      Hbuf, W2t, sW2t, b2, sb2, perm, cnt, (void*)ebuf);
  combine_kernel<<<(T_TOK * D_DIM / 4) / 256, 256, 0, stream>>>(ebuf, scores, pbuf, idx, out);
}

// Round 2
// 387.822 us; speedup vs baseline: 1.7398x; 1.7398x over previous
//
#include <hip/hip_runtime.h>
#include <math.h>

#define T_TOK 4096
#define D_DIM 1024
#define H_DIM 2048
#define NE 8
#define EPSF 1e-8f
#define MAXT 104  // worst-case M-tiles: experts <=71 (+pad) + shared 32; multiple of 8

typedef __attribute__((ext_vector_type(8))) short bf16x8;
typedef __attribute__((ext_vector_type(4))) float f32x4;

__device__ __forceinline__ unsigned short f2bf(float f) {
  unsigned u = __float_as_uint(f);
  u += 0x7fffu + ((u >> 16) & 1u);
  return (unsigned short)(u >> 16);
}

__device__ __forceinline__ void gload_lds16(const void* g, void* l) {
  __builtin_amdgcn_global_load_lds(
      (const __attribute__((address_space(1))) unsigned int*)g,
      (__attribute__((address_space(3))) unsigned int*)l, 16, 0, 0);
}

// ---------------------------------------------------------------- small init
__global__ void zero_small_kernel(unsigned* cnt, unsigned* usage) {
  if (threadIdx.x < NE) { cnt[threadIdx.x] = 0u; usage[threadIdx.x] = 0u; }
}

// ---------------------------------------------------------------- cast x -> bf16
__global__ void cast_x_kernel(const float* __restrict__ x, unsigned short* __restrict__ xb) {
  int id = blockIdx.x * blockDim.x + threadIdx.x;  // one uint4 (8 bf16) per thread
  const float4* src = (const float4*)x;
  float4 a = src[id * 2], b = src[id * 2 + 1];
  union { unsigned short u[8]; uint4 v; } o;
  o.u[0] = f2bf(a.x); o.u[1] = f2bf(a.y); o.u[2] = f2bf(a.z); o.u[3] = f2bf(a.w);
  o.u[4] = f2bf(b.x); o.u[5] = f2bf(b.y); o.u[6] = f2bf(b.z); o.u[7] = f2bf(b.w);
  ((uint4*)xb)[id] = o.v;
}

// ---------------------------------------------------------------- transpose + cast weights
template <int R, int C>
__global__ void transpose_cast_kernel(const float* __restrict__ srcE, const float* __restrict__ srcS,
                                      unsigned short* __restrict__ dstE, unsigned short* __restrict__ dstS) {
  __shared__ float tile[64][65];
  int m = blockIdx.z;
  const float* src = (m < NE) ? srcE + (size_t)m * R * C : srcS;
  unsigned short* dst = (m < NE) ? dstE + (size_t)m * R * C : dstS;
  int r0 = blockIdx.y * 64, c0 = blockIdx.x * 64;
  int tid = threadIdx.x;
#pragma unroll
  for (int k = 0; k < 4; ++k) {
    int id = tid + k * 256;
    int row = id >> 4, c4 = (id & 15) * 4;
    float4 v = *(const float4*)(src + (size_t)(r0 + row) * C + c0 + c4);
    tile[row][c4 + 0] = v.x; tile[row][c4 + 1] = v.y;
    tile[row][c4 + 2] = v.z; tile[row][c4 + 3] = v.w;
  }
  __syncthreads();
#pragma unroll
  for (int k = 0; k < 2; ++k) {
    int id = tid + k * 256;
    int oc = id >> 3, rbase = (id & 7) * 8;
    uint4 w;
    unsigned* wp = (unsigned*)&w;
#pragma unroll
    for (int j = 0; j < 4; ++j) {
      unsigned lo = f2bf(tile[rbase + 2 * j][oc]);
      unsigned hi = f2bf(tile[rbase + 2 * j + 1][oc]);
      wp[j] = lo | (hi << 16);
    }
    *(uint4*)(dst + (size_t)(c0 + oc) * R + r0 + rbase) = w;
  }
}

// ---------------------------------------------------------------- gating
__global__ void gate_kernel(const float* __restrict__ x, const float* __restrict__ gW,
                            const float* __restrict__ gb, const float* __restrict__ gtemp,
                            float* __restrict__ scores, int* __restrict__ idx,
                            unsigned* __restrict__ usage) {
  int wave = threadIdx.x >> 6, lane = threadIdx.x & 63;
  int t = blockIdx.x * 4 + wave;
  float part[NE];
#pragma unroll
  for (int e = 0; e < NE; ++e) part[e] = 0.f;
  const float* xr = x + (size_t)t * D_DIM;
  for (int d = lane; d < D_DIM; d += 64) {
    float xv = xr[d];
    const float* g = gW + (size_t)d * NE;
#pragma unroll
    for (int e = 0; e < NE; ++e) part[e] += xv * g[e];
  }
#pragma unroll
  for (int e = 0; e < NE; ++e) {
    float v = part[e];
    for (int off = 32; off; off >>= 1) v += __shfl_xor(v, off);
    part[e] = v;
  }
  float temp = gtemp[0];
  float mx = -1e30f;
#pragma unroll
  for (int e = 0; e < NE; ++e) { part[e] = (part[e] + gb[e]) / temp; mx = fmaxf(mx, part[e]); }
  float s = 0.f;
#pragma unroll
  for (int e = 0; e < NE; ++e) { part[e] = expf(part[e] - mx); s += part[e]; }
  float inv = 1.0f / s;
#pragma unroll
  for (int e = 0; e < NE; ++e) part[e] *= inv;
  if (lane == 0) {
    float4* sp = (float4*)(scores + (size_t)t * NE);
    sp[0] = make_float4(part[0], part[1], part[2], part[3]);
    sp[1] = make_float4(part[4], part[5], part[6], part[7]);
    int i0 = 0; float b0 = part[0];
#pragma unroll
    for (int e = 1; e < NE; ++e) if (part[e] > b0) { b0 = part[e]; i0 = e; }
    int i1 = -1; float b1 = -1e30f;
#pragma unroll
    for (int e = 0; e < NE; ++e) if (e != i0 && part[e] > b1) { b1 = part[e]; i1 = e; }
    idx[t * 2] = i0; idx[t * 2 + 1] = i1;
    atomicAdd(&usage[i0], 1u);
  }
}

// ---------------------------------------------------------------- EM (5 iters) + KL loss
__global__ void em_loss_kernel(const float* __restrict__ scores, const unsigned* __restrict__ usage,
                               float* __restrict__ p_out, float* __restrict__ loss_out) {
  __shared__ float p_sh[NE];
  __shared__ float cw[16][NE];
  __shared__ float counts_sh[NE];
  int tid = threadIdx.x, wave = tid >> 6, lane = tid & 63;
  float s[4][NE];
#pragma unroll
  for (int rr = 0; rr < 4; ++rr) {
    int row = tid + rr * 1024;
    const float4* sp = (const float4*)(scores + (size_t)row * NE);
    float4 a = sp[0], b = sp[1];
    s[rr][0] = a.x; s[rr][1] = a.y; s[rr][2] = a.z; s[rr][3] = a.w;
    s[rr][4] = b.x; s[rr][5] = b.y; s[rr][6] = b.z; s[rr][7] = b.w;
  }
  if (tid < NE) p_sh[tid] = 1.0f / NE;
  __syncthreads();
  for (int it = 0; it < 5; ++it) {
    float p[NE];
#pragma unroll
    for (int e = 0; e < NE; ++e) p[e] = p_sh[e];
    float c[NE];
#pragma unroll
    for (int e = 0; e < NE; ++e) c[e] = 0.f;
#pragma unroll
    for (int rr = 0; rr < 4; ++rr) {
      float denom = 0.f;
#pragma unroll
      for (int e = 0; e < NE; ++e) denom += s[rr][e] * p[e];
      float inv = 1.0f / (denom + EPSF);
#pragma unroll
      for (int e = 0; e < NE; ++e) c[e] += s[rr][e] * p[e] * inv;
    }
#pragma unroll
    for (int e = 0; e < NE; ++e) {
      float v = c[e];
      for (int off = 32; off; off >>= 1) v += __shfl_xor(v, off);
      c[e] = v;
    }
    if (lane == 0) {
#pragma unroll
      for (int e = 0; e < NE; ++e) cw[wave][e] = c[e];
    }
    __syncthreads();
    if (tid < NE) {
      float tot = 0.f;
#pragma unroll
      for (int w = 0; w < 16; ++w) tot += cw[w][tid];
      counts_sh[tid] = tot;
    }
    __syncthreads();
    if (tid < NE) {
      float total = 0.f;
#pragma unroll
      for (int e = 0; e < NE; ++e) total += counts_sh[e];
      p_sh[tid] = counts_sh[tid] / (total + EPSF);
    }
    __syncthreads();
  }
  if (tid < NE) p_out[tid] = p_sh[tid];
  if (tid == 0) {
    float actual[NE]; float norm = 0.f;
#pragma unroll
    for (int e = 0; e < NE; ++e) { actual[e] = (float)usage[e] / (float)T_TOK + EPSF; norm += actual[e]; }
    float u = 1.0f / NE;
    float kl = 0.f;
#pragma unroll
    for (int e = 0; e < NE; ++e) kl += u * (logf(u) - logf(actual[e] / norm));
    loss_out[0] = 0.1f * kl;
  }
}

// ---------------------------------------------------------------- scatter tokens to expert lists
__global__ void scatter_kernel(const int* __restrict__ idx, unsigned* __restrict__ cnt,
                               int* __restrict__ perm) {
  int t = blockIdx.x * blockDim.x + threadIdx.x;
#pragma unroll
  for (int k = 0; k < 2; ++k) {
    int e = idx[t * 2 + k];
    unsigned pos = atomicAdd(&cnt[e], 1u);
    perm[(size_t)e * T_TOK + pos] = t * 2 + k;
  }
}

// ---------------------------------------------------------------- plan: dense tile worklist
__global__ void plan_kernel(const unsigned* __restrict__ cnt, int* __restrict__ work,
                            int* __restrict__ ntiles) {
  if (threadIdx.x == 0) {
    int n = 0;
    for (int e = 0; e < NE; ++e) {
      int t = ((int)cnt[e] + 127) >> 7;
      for (int m = 0; m < t; ++m) work[n++] = (e << 8) | m;
    }
    for (int m = 0; m < T_TOK / 128; ++m) work[n++] = (NE << 8) | m;
    ntiles[0] = n;
  }
}

// ---------------------------------------------------------------- gathered bf16 MFMA GEMM
// Work-list driven, XCD-chunked: each XCD gets a contiguous run of
// (tile-outer, n0-inner) work items -> B panels read once per XCD, A panels
// reused across the n0 sweep inside the resident window.
template <int KDIM, int NDIM, bool RELU, bool MODE1>
__global__ __launch_bounds__(256) void gemm_kernel(
    const unsigned short* __restrict__ A, const unsigned short* __restrict__ WE,
    const unsigned short* __restrict__ WS, const float* __restrict__ biasE,
    const float* __restrict__ biasS, const int* __restrict__ perm,
    const unsigned* __restrict__ cnt, const int* __restrict__ work,
    const int* __restrict__ ntiles, void* __restrict__ outp) {
  constexpr int BM = 128, BN = 128, BK = 64;
  constexpr int NT = NDIM / BN;

  // ---- runtime-bijective XCD chunking (m204 formula) ----
  int flat = blockIdx.y * MAXT + blockIdx.x;  // hw dispatch order (x fastest)
  int xcd = flat & 7, pos = flat >> 3;
  int W = ntiles[0] * NT;
  int q = W >> 3, r = W & 7;
  int mycount = q + (xcd < r ? 1 : 0);
  if (pos >= mycount) return;
  int mystart = xcd * q + (xcd < r ? xcd : r);
  int w = mystart + pos;
  int tileIdx = w / NT;          // compile-time NT -> cheap
  int n0 = (w % NT) * BN;
  int packed = work[tileIdx];
  int e = packed >> 8, mt = packed & 255;
  int m0 = mt * BM;
  int cnt_e = (e == NE) ? T_TOK : (int)cnt[e];

  const unsigned short* Bmat = (e == NE) ? WS : WE + (size_t)e * KDIM * NDIM;
  const float* bias = (e == NE) ? biasS : biasE + (size_t)e * NDIM;

  __shared__ unsigned short As[BM * BK];
  __shared__ unsigned short Bs[BN * BK];

  int tid = threadIdx.x, wave = tid >> 6, lane = tid & 63;
  int wm = wave >> 1, wn = wave & 1;
  int lrow = lane >> 3;
  int lcol = (lane & 7) * 8;

  int asrc[4];
#pragma unroll
  for (int c = 0; c < 4; ++c) {
    int row = wave * 32 + c * 8 + lrow;
    int rr = m0 + row;
    if (rr > cnt_e - 1) rr = cnt_e - 1;
    if (e == NE) {
      asrc[c] = MODE1 ? rr : (2 * T_TOK + rr);
    } else {
      int v = perm[(size_t)e * T_TOK + rr];
      asrc[c] = MODE1 ? (v >> 1) : v;
    }
  }

  f32x4 acc[4][4];
#pragma unroll
  for (int i = 0; i < 4; ++i)
#pragma unroll
    for (int j = 0; j < 4; ++j) acc[i][j] = (f32x4){0.f, 0.f, 0.f, 0.f};

  for (int k0 = 0; k0 < KDIM; k0 += BK) {
#pragma unroll
    for (int c = 0; c < 4; ++c) {
      const unsigned short* g = A + (size_t)asrc[c] * KDIM + k0 + lcol;
      gload_lds16(g, &As[(wave * 32 + c * 8) * BK]);
    }
#pragma unroll
    for (int c = 0; c < 4; ++c) {
      int nrow = wave * 32 + c * 8 + lrow;
      const unsigned short* g = Bmat + (size_t)(n0 + nrow) * KDIM + k0 + lcol;
      gload_lds16(g, &Bs[(wave * 32 + c * 8) * BK]);
    }
    __syncthreads();
#pragma unroll
    for (int kk = 0; kk < BK; kk += 32) {
      bf16x8 af[4], bfr[4];
#pragma unroll
      for (int i = 0; i < 4; ++i)
        af[i] = *(const bf16x8*)&As[(wm * 64 + i * 16 + (lane & 15)) * BK + kk + (lane >> 4) * 8];
#pragma unroll
      for (int j = 0; j < 4; ++j)
        bfr[j] = *(const bf16x8*)&Bs[(wn * 64 + j * 16 + (lane & 15)) * BK + kk + (lane >> 4) * 8];
#pragma unroll
      for (int i = 0; i < 4; ++i)
#pragma unroll
        for (int j = 0; j < 4; ++j)
          acc[i][j] = __builtin_amdgcn_mfma_f32_16x16x32_bf16(af[i], bfr[j], acc[i][j], 0, 0, 0);
    }
    __syncthreads();
  }

#pragma unroll
  for (int i = 0; i < 4; ++i) {
#pragma unroll
    for (int q2 = 0; q2 < 4; ++q2) {
      int rt = wm * 64 + i * 16 + (lane >> 4) * 4 + q2;
      if (m0 + rt >= cnt_e) continue;
      int rr;
      if (e == NE) rr = 2 * T_TOK + m0 + rt;
      else rr = perm[(size_t)e * T_TOK + m0 + rt];
#pragma unroll
      for (int j = 0; j < 4; ++j) {
        int col = n0 + wn * 64 + j * 16 + (lane & 15);
        float val = acc[i][j][q2] + bias[col];
        if (RELU) val = fmaxf(val, 0.f);
        if (MODE1)
          ((unsigned short*)outp)[(size_t)rr * NDIM + col] = f2bf(val);
        else
          ((float*)outp)[(size_t)rr * NDIM + col] = val;
      }
    }
  }
}

// ---------------------------------------------------------------- combine
__global__ void combine_kernel(const float* __restrict__ ebuf, const float* __restrict__ scores,
                               const float* __restrict__ p, const int* __restrict__ idx,
                               float* __restrict__ out) {
  int gid = blockIdx.x * blockDim.x + threadIdx.x;
  int t = gid >> 8;
  int d4 = gid & 255;
  int e0 = idx[t * 2], e1 = idx[t * 2 + 1];
  float w0 = scores[(size_t)t * NE + e0] * p[e0];
  float w1 = scores[(size_t)t * NE + e1] * p[e1];
  const float4* r0 = (const float4*)(ebuf + (size_t)(t * 2) * D_DIM);
  const float4* r1 = (const float4*)(ebuf + (size_t)(t * 2 + 1) * D_DIM);
  const float4* rs = (const float4*)(ebuf + (size_t)(2 * T_TOK + t) * D_DIM);
  float4 a = r0[d4], b = r1[d4], c = rs[d4];
  float4 o;
  o.x = w0 * a.x + w1 * b.x + 0.1f * c.x;
  o.y = w0 * a.y + w1 * b.y + 0.1f * c.y;
  o.z = w0 * a.z + w1 * b.z + 0.1f * c.z;
  o.w = w0 * a.w + w1 * b.w + 0.1f * c.w;
  ((float4*)out)[gid] = o;
}

// ---------------------------------------------------------------- launch
extern "C" void kernel_launch(void* const* d_in, const int* in_sizes, int n_in,
                              void* d_out, int out_size, void* d_ws, size_t ws_size,
                              hipStream_t stream) {
  const float* x     = (const float*)d_in[0];
  const float* gW    = (const float*)d_in[1];
  const float* gb    = (const float*)d_in[2];
  const float* gtemp = (const float*)d_in[3];
  const float* W1    = (const float*)d_in[4];
  const float* b1    = (const float*)d_in[5];
  const float* W2    = (const float*)d_in[6];
  const float* b2    = (const float*)d_in[7];
  const float* sW1   = (const float*)d_in[8];
  const float* sb1   = (const float*)d_in[9];
  const float* sW2   = (const float*)d_in[10];
  const float* sb2   = (const float*)d_in[11];
  float* out = (float*)d_out;

  char* ws = (char*)d_ws;
  size_t off = 0;
  auto take = [&](size_t b) { char* ptr = ws + off; off += (b + 255) & ~(size_t)255; return ptr; };
  unsigned short* xb   = (unsigned short*)take((size_t)T_TOK * D_DIM * 2);
  unsigned short* W1t  = (unsigned short*)take((size_t)NE * H_DIM * D_DIM * 2);
  unsigned short* sW1t = (unsigned short*)take((size_t)H_DIM * D_DIM * 2);
  unsigned short* W2t  = (unsigned short*)take((size_t)NE * D_DIM * H_DIM * 2);
  unsigned short* sW2t = (unsigned short*)take((size_t)D_DIM * H_DIM * 2);
  unsigned short* Hbuf = (unsigned short*)take((size_t)3 * T_TOK * H_DIM * 2);
  float* ebuf          = (float*)take((size_t)3 * T_TOK * D_DIM * 4);
  float* scores        = (float*)take((size_t)T_TOK * NE * 4);
  int* idx             = (int*)take((size_t)T_TOK * 2 * 4);
  int* perm            = (int*)take((size_t)NE * T_TOK * 4);
  unsigned* cnt        = (unsigned*)take(256);
  unsigned* usage      = (unsigned*)take(256);
  float* pbuf          = (float*)take(256);
  int* work            = (int*)take(MAXT * 4);
  int* ntiles          = (int*)take(256);
  (void)n_in; (void)in_sizes; (void)out_size; (void)ws_size;

  zero_small_kernel<<<1, 64, 0, stream>>>(cnt, usage);
  cast_x_kernel<<<(T_TOK * D_DIM / 8) / 256, 256, 0, stream>>>(x, xb);
  transpose_cast_kernel<D_DIM, H_DIM><<<dim3(H_DIM / 64, D_DIM / 64, 9), 256, 0, stream>>>(W1, sW1, W1t, sW1t);
  transpose_cast_kernel<H_DIM, D_DIM><<<dim3(D_DIM / 64, H_DIM / 64, 9), 256, 0, stream>>>(W2, sW2, W2t, sW2t);
  gate_kernel<<<T_TOK / 4, 256, 0, stream>>>(x, gW, gb, gtemp, scores, idx, usage);
  em_loss_kernel<<<1, 1024, 0, stream>>>(scores, usage, pbuf, out + (size_t)T_TOK * D_DIM);
  scatter_kernel<<<T_TOK / 256, 256, 0, stream>>>(idx, cnt, perm);
  plan_kernel<<<1, 64, 0, stream>>>(cnt, work, ntiles);
  gemm_kernel<D_DIM, H_DIM, true, true><<<dim3(MAXT, H_DIM / 128), 256, 0, stream>>>(
      xb, W1t, sW1t, b1, sb1, perm, cnt, work, ntiles, (void*)Hbuf);
  gemm_kernel<H_DIM, D_DIM, false, false><<<dim3(MAXT, D_DIM / 128), 256, 0, stream>>>(
      Hbuf, W2t, sW2t, b2, sb2, perm, cnt, work, ntiles, (void*)ebuf);
  combine_kernel<<<(T_TOK * D_DIM / 4) / 256, 256, 0, stream>>>(ebuf, scores, pbuf, idx, out);
}

// Round 3
// 299.154 us; speedup vs baseline: 2.2554x; 1.2964x over previous
//
#include <hip/hip_runtime.h>
#include <math.h>

#define T_TOK 4096
#define D_DIM 1024
#define H_DIM 2048
#define NE 8
#define EPSF 1e-8f
#define MAXT 56  // worst-case 256-row M-tiles: experts <=39 + shared 16 -> 55

typedef __attribute__((ext_vector_type(8))) short bf16x8;
typedef __attribute__((ext_vector_type(4))) float f32x4;

__device__ __forceinline__ unsigned short f2bf(float f) {
  unsigned u = __float_as_uint(f);
  u += 0x7fffu + ((u >> 16) & 1u);
  return (unsigned short)(u >> 16);
}

__device__ __forceinline__ void gload_lds16(const void* g, void* l) {
  __builtin_amdgcn_global_load_lds(
      (const __attribute__((address_space(1))) unsigned int*)g,
      (__attribute__((address_space(3))) unsigned int*)l, 16, 0, 0);
}

#define WAITV(n) asm volatile("s_waitcnt vmcnt(" #n ")" ::: "memory")
#define BARR()                                  \
  do {                                          \
    asm volatile("" ::: "memory");              \
    __builtin_amdgcn_s_barrier();               \
    asm volatile("" ::: "memory");              \
  } while (0)

// ---------------------------------------------------------------- small init
__global__ void zero_small_kernel(unsigned* cnt, unsigned* usage) {
  if (threadIdx.x < NE) { cnt[threadIdx.x] = 0u; usage[threadIdx.x] = 0u; }
}

// ---------------------------------------------------------------- cast x -> bf16
__global__ void cast_x_kernel(const float* __restrict__ x, unsigned short* __restrict__ xb) {
  int id = blockIdx.x * blockDim.x + threadIdx.x;
  const float4* src = (const float4*)x;
  float4 a = src[id * 2], b = src[id * 2 + 1];
  union { unsigned short u[8]; uint4 v; } o;
  o.u[0] = f2bf(a.x); o.u[1] = f2bf(a.y); o.u[2] = f2bf(a.z); o.u[3] = f2bf(a.w);
  o.u[4] = f2bf(b.x); o.u[5] = f2bf(b.y); o.u[6] = f2bf(b.z); o.u[7] = f2bf(b.w);
  ((uint4*)xb)[id] = o.v;
}

// ---------------------------------------------------------------- transpose + cast weights
template <int R, int C>
__global__ void transpose_cast_kernel(const float* __restrict__ srcE, const float* __restrict__ srcS,
                                      unsigned short* __restrict__ dstE, unsigned short* __restrict__ dstS) {
  __shared__ float tile[64][65];
  int m = blockIdx.z;
  const float* src = (m < NE) ? srcE + (size_t)m * R * C : srcS;
  unsigned short* dst = (m < NE) ? dstE + (size_t)m * R * C : dstS;
  int r0 = blockIdx.y * 64, c0 = blockIdx.x * 64;
  int tid = threadIdx.x;
#pragma unroll
  for (int k = 0; k < 4; ++k) {
    int id = tid + k * 256;
    int row = id >> 4, c4 = (id & 15) * 4;
    float4 v = *(const float4*)(src + (size_t)(r0 + row) * C + c0 + c4);
    tile[row][c4 + 0] = v.x; tile[row][c4 + 1] = v.y;
    tile[row][c4 + 2] = v.z; tile[row][c4 + 3] = v.w;
  }
  __syncthreads();
#pragma unroll
  for (int k = 0; k < 2; ++k) {
    int id = tid + k * 256;
    int oc = id >> 3, rbase = (id & 7) * 8;
    uint4 w;
    unsigned* wp = (unsigned*)&w;
#pragma unroll
    for (int j = 0; j < 4; ++j) {
      unsigned lo = f2bf(tile[rbase + 2 * j][oc]);
      unsigned hi = f2bf(tile[rbase + 2 * j + 1][oc]);
      wp[j] = lo | (hi << 16);
    }
    *(uint4*)(dst + (size_t)(c0 + oc) * R + r0 + rbase) = w;
  }
}

// ---------------------------------------------------------------- gating
__global__ void gate_kernel(const float* __restrict__ x, const float* __restrict__ gW,
                            const float* __restrict__ gb, const float* __restrict__ gtemp,
                            float* __restrict__ scores, int* __restrict__ idx,
                            unsigned* __restrict__ usage) {
  int wave = threadIdx.x >> 6, lane = threadIdx.x & 63;
  int t = blockIdx.x * 4 + wave;
  float part[NE];
#pragma unroll
  for (int e = 0; e < NE; ++e) part[e] = 0.f;
  const float* xr = x + (size_t)t * D_DIM;
  for (int d = lane; d < D_DIM; d += 64) {
    float xv = xr[d];
    const float* g = gW + (size_t)d * NE;
#pragma unroll
    for (int e = 0; e < NE; ++e) part[e] += xv * g[e];
  }
#pragma unroll
  for (int e = 0; e < NE; ++e) {
    float v = part[e];
    for (int off = 32; off; off >>= 1) v += __shfl_xor(v, off);
    part[e] = v;
  }
  float temp = gtemp[0];
  float mx = -1e30f;
#pragma unroll
  for (int e = 0; e < NE; ++e) { part[e] = (part[e] + gb[e]) / temp; mx = fmaxf(mx, part[e]); }
  float s = 0.f;
#pragma unroll
  for (int e = 0; e < NE; ++e) { part[e] = expf(part[e] - mx); s += part[e]; }
  float inv = 1.0f / s;
#pragma unroll
  for (int e = 0; e < NE; ++e) part[e] *= inv;
  if (lane == 0) {
    float4* sp = (float4*)(scores + (size_t)t * NE);
    sp[0] = make_float4(part[0], part[1], part[2], part[3]);
    sp[1] = make_float4(part[4], part[5], part[6], part[7]);
    int i0 = 0; float b0 = part[0];
#pragma unroll
    for (int e = 1; e < NE; ++e) if (part[e] > b0) { b0 = part[e]; i0 = e; }
    int i1 = -1; float b1 = -1e30f;
#pragma unroll
    for (int e = 0; e < NE; ++e) if (e != i0 && part[e] > b1) { b1 = part[e]; i1 = e; }
    idx[t * 2] = i0; idx[t * 2 + 1] = i1;
    atomicAdd(&usage[i0], 1u);
  }
}

// ---------------------------------------------------------------- EM (5 iters) + KL loss
__global__ void em_loss_kernel(const float* __restrict__ scores, const unsigned* __restrict__ usage,
                               float* __restrict__ p_out, float* __restrict__ loss_out) {
  __shared__ float p_sh[NE];
  __shared__ float cw[16][NE];
  __shared__ float counts_sh[NE];
  int tid = threadIdx.x, wave = tid >> 6, lane = tid & 63;
  float s[4][NE];
#pragma unroll
  for (int rr = 0; rr < 4; ++rr) {
    int row = tid + rr * 1024;
    const float4* sp = (const float4*)(scores + (size_t)row * NE);
    float4 a = sp[0], b = sp[1];
    s[rr][0] = a.x; s[rr][1] = a.y; s[rr][2] = a.z; s[rr][3] = a.w;
    s[rr][4] = b.x; s[rr][5] = b.y; s[rr][6] = b.z; s[rr][7] = b.w;
  }
  if (tid < NE) p_sh[tid] = 1.0f / NE;
  __syncthreads();
  for (int it = 0; it < 5; ++it) {
    float p[NE];
#pragma unroll
    for (int e = 0; e < NE; ++e) p[e] = p_sh[e];
    float c[NE];
#pragma unroll
    for (int e = 0; e < NE; ++e) c[e] = 0.f;
#pragma unroll
    for (int rr = 0; rr < 4; ++rr) {
      float denom = 0.f;
#pragma unroll
      for (int e = 0; e < NE; ++e) denom += s[rr][e] * p[e];
      float inv = 1.0f / (denom + EPSF);
#pragma unroll
      for (int e = 0; e < NE; ++e) c[e] += s[rr][e] * p[e] * inv;
    }
#pragma unroll
    for (int e = 0; e < NE; ++e) {
      float v = c[e];
      for (int off = 32; off; off >>= 1) v += __shfl_xor(v, off);
      c[e] = v;
    }
    if (lane == 0) {
#pragma unroll
      for (int e = 0; e < NE; ++e) cw[wave][e] = c[e];
    }
    __syncthreads();
    if (tid < NE) {
      float tot = 0.f;
#pragma unroll
      for (int w = 0; w < 16; ++w) tot += cw[w][tid];
      counts_sh[tid] = tot;
    }
    __syncthreads();
    if (tid < NE) {
      float total = 0.f;
#pragma unroll
      for (int e = 0; e < NE; ++e) total += counts_sh[e];
      p_sh[tid] = counts_sh[tid] / (total + EPSF);
    }
    __syncthreads();
  }
  if (tid < NE) p_out[tid] = p_sh[tid];
  if (tid == 0) {
    float actual[NE]; float norm = 0.f;
#pragma unroll
    for (int e = 0; e < NE; ++e) { actual[e] = (float)usage[e] / (float)T_TOK + EPSF; norm += actual[e]; }
    float u = 1.0f / NE;
    float kl = 0.f;
#pragma unroll
    for (int e = 0; e < NE; ++e) kl += u * (logf(u) - logf(actual[e] / norm));
    loss_out[0] = 0.1f * kl;
  }
}

// ---------------------------------------------------------------- scatter tokens to expert lists
__global__ void scatter_kernel(const int* __restrict__ idx, unsigned* __restrict__ cnt,
                               int* __restrict__ perm) {
  int t = blockIdx.x * blockDim.x + threadIdx.x;
#pragma unroll
  for (int k = 0; k < 2; ++k) {
    int e = idx[t * 2 + k];
    unsigned pos = atomicAdd(&cnt[e], 1u);
    perm[(size_t)e * T_TOK + pos] = t * 2 + k;
  }
}

// ---------------------------------------------------------------- plan: dense tile worklist (BM=256)
__global__ void plan_kernel(const unsigned* __restrict__ cnt, int* __restrict__ work,
                            int* __restrict__ ntiles) {
  if (threadIdx.x == 0) {
    int n = 0;
    for (int e = 0; e < NE; ++e) {
      int t = ((int)cnt[e] + 255) >> 8;
      for (int m = 0; m < t; ++m) work[n++] = (e << 8) | m;
    }
    for (int m = 0; m < T_TOK / 256; ++m) work[n++] = (NE << 8) | m;
    ntiles[0] = n;
  }
}

// ---------------------------------------------------------------- 256x256 8-phase MFMA GEMM
// 8 waves (4M x 2N), BK=64, double-buffered 128KB LDS, T2 st-swizzle
// (slot ^= row&7 on 16B slots, pre-swizzled global source for the linear
// global_load_lds dest), counted vmcnt twice per K-tile, setprio around MFMA.
// Half-tile stage schedule: ph1: B0(t+1), ph2: B1(t+1), ph3: A0(t+2), ph4: A1(t+2).
template <int KDIM, int NDIM, bool RELU, bool MODE1>
__global__ __launch_bounds__(512, 2) void gemm8p_kernel(
    const unsigned short* __restrict__ A, const unsigned short* __restrict__ WE,
    const unsigned short* __restrict__ WS, const float* __restrict__ biasE,
    const float* __restrict__ biasS, const int* __restrict__ perm,
    const unsigned* __restrict__ cnt, const int* __restrict__ work,
    const int* __restrict__ ntiles, void* __restrict__ outp) {
  constexpr int BM = 256, BN = 256, BK = 64;
  constexpr int NT = NDIM / BN;
  constexpr int NKT = KDIM / BK;

  __shared__ unsigned short lds[65536];  // 128 KB: A[2][256][64] then B[2][256][64]

  int flat = blockIdx.y * gridDim.x + blockIdx.x;
  int xcd = flat & 7, pos = flat >> 3;
  int W = ntiles[0] * NT;
  int q = W >> 3, r = W & 7;
  int mycount = q + (xcd < r ? 1 : 0);
  if (pos >= mycount) return;
  int mystart = xcd * q + (xcd < r ? xcd : r);
  int w = mystart + pos;
  int tileIdx = w / NT;
  int n0 = (w % NT) * BN;
  int packed = work[tileIdx];
  int e = packed >> 8, mt = packed & 255;
  int m0 = mt * BM;
  int cnt_e = (e == NE) ? T_TOK : (int)cnt[e];

  const unsigned short* Bmat = (e == NE) ? WS : WE + (size_t)e * KDIM * NDIM;
  const float* bias = (e == NE) ? biasS : biasE + (size_t)e * NDIM;

  int tid = threadIdx.x, wave = tid >> 6, lane = tid & 63;
  int wm = wave >> 1, wn = wave & 1;
  int frow = lane & 15, fks = lane >> 4;

  // ---- staging pointers: thread stages rows r = h*128 + j*64 + wave*8 + (lane>>3),
  //      16B slot (lane&7), source column pre-swizzled by (slot ^ (r&7)).
  int srow = wave * 8 + (lane >> 3);
  int sslot = lane & 7;
  const unsigned short* aptr[2][2];
  const unsigned short* bptr[2][2];
#pragma unroll
  for (int h = 0; h < 2; ++h)
#pragma unroll
    for (int j = 0; j < 2; ++j) {
      int rr = h * 128 + j * 64 + srow;
      int colsw = (sslot ^ (rr & 7)) << 3;
      int ar = m0 + rr;
      if (ar > cnt_e - 1) ar = cnt_e - 1;
      int gar;
      if (e == NE) gar = MODE1 ? ar : (2 * T_TOK + ar);
      else { int v = perm[(size_t)e * T_TOK + ar]; gar = MODE1 ? (v >> 1) : v; }
      aptr[h][j] = A + (size_t)gar * KDIM + colsw;
      bptr[h][j] = Bmat + (size_t)(n0 + rr) * KDIM + colsw;
    }

  auto stA = [&](int t, int h) {
    int dbe = (t & 1) * 16384;
    int k0 = t * BK;
    gload_lds16(aptr[h][0] + k0, &lds[dbe + h * 8192 + wave * 512]);
    gload_lds16(aptr[h][1] + k0, &lds[dbe + h * 8192 + wave * 512 + 4096]);
  };
  auto stB = [&](int t, int h) {
    int dbe = (t & 1) * 16384;
    int k0 = t * BK;
    gload_lds16(bptr[h][0] + k0, &lds[32768 + dbe + h * 8192 + wave * 512]);
    gload_lds16(bptr[h][1] + k0, &lds[32768 + dbe + h * 8192 + wave * 512 + 4096]);
  };

  // ---- swizzled fragment reads (ds_read_b128, 2-way max bank aliasing)
  auto rdA = [&](int dbe, int ks, int m) -> bf16x8 {
    int rr = wm * 64 + m * 16 + frow;
    int slot = (ks * 4 + fks) ^ (rr & 7);
    return *(const bf16x8*)&lds[dbe + rr * 64 + slot * 8];
  };
  auto rdB = [&](int dbe, int ks, int bh, int jj) -> bf16x8 {
    int rr = bh * 128 + jj * 32 + wn * 16 + frow;
    int slot = (ks * 4 + fks) ^ (rr & 7);
    return *(const bf16x8*)&lds[32768 + dbe + rr * 64 + slot * 8];
  };

  f32x4 acc[4][8];
#pragma unroll
  for (int m = 0; m < 4; ++m)
#pragma unroll
    for (int nn = 0; nn < 8; ++nn) acc[m][nn] = (f32x4){0.f, 0.f, 0.f, 0.f};

  // ---- prologue: issue in steady-state age order, then drain 3 oldest halves
  stA(0, 0); stA(0, 1);
  stB(0, 0); stB(0, 1);
  stA(1, 0); stA(1, 1);
  WAITV(6);
  BARR();

  for (int t = 0; t < NKT; ++t) {
    const int dbe = (t & 1) * 16384;
    bf16x8 a0[4], a1[4], bfr[4];

    // ---- ph1 (B-half0, ksub0)
#pragma unroll
    for (int m = 0; m < 4; ++m) a0[m] = rdA(dbe, 0, m);
#pragma unroll
    for (int jj = 0; jj < 4; ++jj) bfr[jj] = rdB(dbe, 0, 0, jj);
    if (t + 1 < NKT) stB(t + 1, 0);
    BARR();
    __builtin_amdgcn_s_setprio(1);
#pragma unroll
    for (int m = 0; m < 4; ++m)
#pragma unroll
      for (int jj = 0; jj < 4; ++jj)
        acc[m][jj] = __builtin_amdgcn_mfma_f32_16x16x32_bf16(a0[m], bfr[jj], acc[m][jj], 0, 0, 0);
    __builtin_amdgcn_s_setprio(0);
    BARR();

    // ---- ph2 (B-half0, ksub1)
#pragma unroll
    for (int m = 0; m < 4; ++m) a1[m] = rdA(dbe, 1, m);
#pragma unroll
    for (int jj = 0; jj < 4; ++jj) bfr[jj] = rdB(dbe, 1, 0, jj);
    if (t + 1 < NKT) stB(t + 1, 1);
    BARR();
    __builtin_amdgcn_s_setprio(1);
#pragma unroll
    for (int m = 0; m < 4; ++m)
#pragma unroll
      for (int jj = 0; jj < 4; ++jj)
        acc[m][jj] = __builtin_amdgcn_mfma_f32_16x16x32_bf16(a1[m], bfr[jj], acc[m][jj], 0, 0, 0);
    __builtin_amdgcn_s_setprio(0);
    if (t + 1 < NKT) { WAITV(8); } else { WAITV(0); }  // B-half1(t) resident
    BARR();

    // ---- ph3 (B-half1, ksub0)
#pragma unroll
    for (int jj = 0; jj < 4; ++jj) bfr[jj] = rdB(dbe, 0, 1, jj);
    if (t + 2 < NKT) stA(t + 2, 0);
    BARR();
    __builtin_amdgcn_s_setprio(1);
#pragma unroll
    for (int m = 0; m < 4; ++m)
#pragma unroll
      for (int jj = 0; jj < 4; ++jj)
        acc[m][4 + jj] = __builtin_amdgcn_mfma_f32_16x16x32_bf16(a0[m], bfr[jj], acc[m][4 + jj], 0, 0, 0);
    __builtin_amdgcn_s_setprio(0);
    BARR();

    // ---- ph4 (B-half1, ksub1)
#pragma unroll
    for (int jj = 0; jj < 4; ++jj) bfr[jj] = rdB(dbe, 1, 1, jj);
    if (t + 2 < NKT) stA(t + 2, 1);
    BARR();
    __builtin_amdgcn_s_setprio(1);
#pragma unroll
    for (int m = 0; m < 4; ++m)
#pragma unroll
      for (int jj = 0; jj < 4; ++jj)
        acc[m][4 + jj] = __builtin_amdgcn_mfma_f32_16x16x32_bf16(a1[m], bfr[jj], acc[m][4 + jj], 0, 0, 0);
    __builtin_amdgcn_s_setprio(0);
    if (t + 1 < NKT) {  // boundary: A0,A1,B0 of tile t+1 resident
      if (t + 2 < NKT) { WAITV(6); } else { WAITV(2); }
    }
    BARR();
  }

  // ---- epilogue
#pragma unroll
  for (int m = 0; m < 4; ++m) {
#pragma unroll
    for (int qq = 0; qq < 4; ++qq) {
      int rt = wm * 64 + m * 16 + (lane >> 4) * 4 + qq;
      if (m0 + rt >= cnt_e) continue;
      int rr;
      if (e == NE) rr = 2 * T_TOK + m0 + rt;
      else rr = perm[(size_t)e * T_TOK + m0 + rt];
#pragma unroll
      for (int nn = 0; nn < 8; ++nn) {
        int col = n0 + (nn >> 2) * 128 + (nn & 3) * 32 + wn * 16 + (lane & 15);
        float val = acc[m][nn][qq] + bias[col];
        if (RELU) val = fmaxf(val, 0.f);
        if (MODE1)
          ((unsigned short*)outp)[(size_t)rr * NDIM + col] = f2bf(val);
        else
          ((float*)outp)[(size_t)rr * NDIM + col] = val;
      }
    }
  }
}

// ---------------------------------------------------------------- combine
__global__ void combine_kernel(const float* __restrict__ ebuf, const float* __restrict__ scores,
                               const float* __restrict__ p, const int* __restrict__ idx,
                               float* __restrict__ out) {
  int gid = blockIdx.x * blockDim.x + threadIdx.x;
  int t = gid >> 8;
  int d4 = gid & 255;
  int e0 = idx[t * 2], e1 = idx[t * 2 + 1];
  float w0 = scores[(size_t)t * NE + e0] * p[e0];
  float w1 = scores[(size_t)t * NE + e1] * p[e1];
  const float4* r0 = (const float4*)(ebuf + (size_t)(t * 2) * D_DIM);
  const float4* r1 = (const float4*)(ebuf + (size_t)(t * 2 + 1) * D_DIM);
  const float4* rs = (const float4*)(ebuf + (size_t)(2 * T_TOK + t) * D_DIM);
  float4 a = r0[d4], b = r1[d4], c = rs[d4];
  float4 o;
  o.x = w0 * a.x + w1 * b.x + 0.1f * c.x;
  o.y = w0 * a.y + w1 * b.y + 0.1f * c.y;
  o.z = w0 * a.z + w1 * b.z + 0.1f * c.z;
  o.w = w0 * a.w + w1 * b.w + 0.1f * c.w;
  ((float4*)out)[gid] = o;
}

// ---------------------------------------------------------------- launch
extern "C" void kernel_launch(void* const* d_in, const int* in_sizes, int n_in,
                              void* d_out, int out_size, void* d_ws, size_t ws_size,
                              hipStream_t stream) {
  const float* x     = (const float*)d_in[0];
  const float* gW    = (const float*)d_in[1];
  const float* gb    = (const float*)d_in[2];
  const float* gtemp = (const float*)d_in[3];
  const float* W1    = (const float*)d_in[4];
  const float* b1    = (const float*)d_in[5];
  const float* W2    = (const float*)d_in[6];
  const float* b2    = (const float*)d_in[7];
  const float* sW1   = (const float*)d_in[8];
  const float* sb1   = (const float*)d_in[9];
  const float* sW2   = (const float*)d_in[10];
  const float* sb2   = (const float*)d_in[11];
  float* out = (float*)d_out;

  char* ws = (char*)d_ws;
  size_t off = 0;
  auto take = [&](size_t b) { char* ptr = ws + off; off += (b + 255) & ~(size_t)255; return ptr; };
  unsigned short* xb   = (unsigned short*)take((size_t)T_TOK * D_DIM * 2);
  unsigned short* W1t  = (unsigned short*)take((size_t)NE * H_DIM * D_DIM * 2);
  unsigned short* sW1t = (unsigned short*)take((size_t)H_DIM * D_DIM * 2);
  unsigned short* W2t  = (unsigned short*)take((size_t)NE * D_DIM * H_DIM * 2);
  unsigned short* sW2t = (unsigned short*)take((size_t)D_DIM * H_DIM * 2);
  unsigned short* Hbuf = (unsigned short*)take((size_t)3 * T_TOK * H_DIM * 2);
  float* ebuf          = (float*)take((size_t)3 * T_TOK * D_DIM * 4);
  float* scores        = (float*)take((size_t)T_TOK * NE * 4);
  int* idx             = (int*)take((size_t)T_TOK * 2 * 4);
  int* perm            = (int*)take((size_t)NE * T_TOK * 4);
  unsigned* cnt        = (unsigned*)take(256);
  unsigned* usage      = (unsigned*)take(256);
  float* pbuf          = (float*)take(256);
  int* work            = (int*)take(256 * 4);
  int* ntiles          = (int*)take(256);
  (void)n_in; (void)in_sizes; (void)out_size; (void)ws_size;

  zero_small_kernel<<<1, 64, 0, stream>>>(cnt, usage);
  cast_x_kernel<<<(T_TOK * D_DIM / 8) / 256, 256, 0, stream>>>(x, xb);
  transpose_cast_kernel<D_DIM, H_DIM><<<dim3(H_DIM / 64, D_DIM / 64, 9), 256, 0, stream>>>(W1, sW1, W1t, sW1t);
  transpose_cast_kernel<H_DIM, D_DIM><<<dim3(D_DIM / 64, H_DIM / 64, 9), 256, 0, stream>>>(W2, sW2, W2t, sW2t);
  gate_kernel<<<T_TOK / 4, 256, 0, stream>>>(x, gW, gb, gtemp, scores, idx, usage);
  em_loss_kernel<<<1, 1024, 0, stream>>>(scores, usage, pbuf, out + (size_t)T_TOK * D_DIM);
  scatter_kernel<<<T_TOK / 256, 256, 0, stream>>>(idx, cnt, perm);
  plan_kernel<<<1, 64, 0, stream>>>(cnt, work, ntiles);
  gemm8p_kernel<D_DIM, H_DIM, true, true><<<dim3(MAXT, H_DIM / 256), 512, 0, stream>>>(
      xb, W1t, sW1t, b1, sb1, perm, cnt, work, ntiles, (void*)Hbuf);
  gemm8p_kernel<H_DIM, D_DIM, false, false><<<dim3(MAXT, D_DIM / 256), 512, 0, stream>>>(
      Hbuf, W2t, sW2t, b2, sb2, perm, cnt, work, ntiles, (void*)ebuf);
  combine_kernel<<<(T_TOK * D_DIM / 4) / 256, 256, 0, stream>>>(ebuf, scores, pbuf, idx, out);
}

// Round 4
// 284.714 us; speedup vs baseline: 2.3698x; 1.0507x over previous
//
#include <hip/hip_runtime.h>
#include <math.h>

#define T_TOK 4096
#define D_DIM 1024
#define H_DIM 2048
#define NE 8
#define EPSF 1e-8f
#define G1_GEMM 448   // reserved GEMM work slots in gemm1 grid (56 tiles * 8 n0)
#define G2_GEMM 224   // reserved GEMM work slots in gemm2 grid (56 tiles * 4 n0)
#define NTRANS 4608   // 9 matrices * (2048/64)*(1024/64) 64x64 tiles

typedef __attribute__((ext_vector_type(8))) short bf16x8;
typedef __attribute__((ext_vector_type(4))) float f32x4;

__device__ __forceinline__ unsigned short f2bf(float f) {
  unsigned u = __float_as_uint(f);
  u += 0x7fffu + ((u >> 16) & 1u);
  return (unsigned short)(u >> 16);
}

__device__ __forceinline__ void gload_lds16(const void* g, void* l) {
  __builtin_amdgcn_global_load_lds(
      (const __attribute__((address_space(1))) unsigned int*)g,
      (__attribute__((address_space(3))) unsigned int*)l, 16, 0, 0);
}

#define WAITV(n) asm volatile("s_waitcnt vmcnt(" #n ")" ::: "memory")
#define BARR()                                  \
  do {                                          \
    asm volatile("" ::: "memory");              \
    __builtin_amdgcn_s_barrier();               \
    asm volatile("" ::: "memory");              \
  } while (0)

// ---------------------------------------------------------------- transpose helper
// src (R x C) f32 -> dst (C x R) bf16, one 64x64 tile at (r0, c0). tile = 64*65 floats.
template <int NTHR>
__device__ __forceinline__ void transpose_tile(const float* __restrict__ src,
                                               unsigned short* __restrict__ dst,
                                               int R, int C, int r0, int c0, int tid,
                                               float* tile) {
#pragma unroll
  for (int k = 0; k < 1024 / NTHR; ++k) {
    int id = tid + k * NTHR;
    int row = id >> 4, c4 = (id & 15) * 4;
    float4 v = *(const float4*)(src + (size_t)(r0 + row) * C + c0 + c4);
    tile[row * 65 + c4 + 0] = v.x; tile[row * 65 + c4 + 1] = v.y;
    tile[row * 65 + c4 + 2] = v.z; tile[row * 65 + c4 + 3] = v.w;
  }
  __syncthreads();
#pragma unroll
  for (int k = 0; k < 512 / NTHR; ++k) {
    int id = tid + k * NTHR;
    int oc = id >> 3, rbase = (id & 7) * 8;
    uint4 wv;
    unsigned* wp = (unsigned*)&wv;
#pragma unroll
    for (int j = 0; j < 4; ++j) {
      unsigned lo = f2bf(tile[(rbase + 2 * j) * 65 + oc]);
      unsigned hi = f2bf(tile[(rbase + 2 * j + 1) * 65 + oc]);
      wp[j] = lo | (hi << 16);
    }
    *(uint4*)(dst + (size_t)(c0 + oc) * R + r0 + rbase) = wv;
  }
}

// ---------------------------------------------------------------- prep: gate+scatter | cast_x | transpose W1
// grid: [0,1024) gate, [1024,3072) cast_x, [3072,7680) transpose W1-family
__global__ __launch_bounds__(256) void prep_kernel(
    const float* __restrict__ x, const float* __restrict__ gW, const float* __restrict__ gb,
    const float* __restrict__ gtemp, const float* __restrict__ W1, const float* __restrict__ sW1,
    unsigned short* __restrict__ W1t, unsigned short* __restrict__ sW1t,
    unsigned short* __restrict__ xb, float* __restrict__ scores, int* __restrict__ idx,
    unsigned* __restrict__ usage, unsigned* __restrict__ cnt, int* __restrict__ perm) {
  __shared__ float tile[64 * 65];
  int b = blockIdx.x, tid = threadIdx.x;

  if (b < 1024) {
    // ---- gate + softmax + top2 + scatter
    int wave = tid >> 6, lane = tid & 63;
    int t = b * 4 + wave;
    float part[NE];
#pragma unroll
    for (int e = 0; e < NE; ++e) part[e] = 0.f;
    const float* xr = x + (size_t)t * D_DIM;
    for (int d = lane; d < D_DIM; d += 64) {
      float xv = xr[d];
      const float* g = gW + (size_t)d * NE;
#pragma unroll
      for (int e = 0; e < NE; ++e) part[e] += xv * g[e];
    }
#pragma unroll
    for (int e = 0; e < NE; ++e) {
      float v = part[e];
      for (int off = 32; off; off >>= 1) v += __shfl_xor(v, off);
      part[e] = v;
    }
    float temp = gtemp[0];
    float mx = -1e30f;
#pragma unroll
    for (int e = 0; e < NE; ++e) { part[e] = (part[e] + gb[e]) / temp; mx = fmaxf(mx, part[e]); }
    float s = 0.f;
#pragma unroll
    for (int e = 0; e < NE; ++e) { part[e] = expf(part[e] - mx); s += part[e]; }
    float inv = 1.0f / s;
#pragma unroll
    for (int e = 0; e < NE; ++e) part[e] *= inv;
    if (lane == 0) {
      float4* sp = (float4*)(scores + (size_t)t * NE);
      sp[0] = make_float4(part[0], part[1], part[2], part[3]);
      sp[1] = make_float4(part[4], part[5], part[6], part[7]);
      int i0 = 0; float b0 = part[0];
#pragma unroll
      for (int e = 1; e < NE; ++e) if (part[e] > b0) { b0 = part[e]; i0 = e; }
      int i1 = -1; float b1 = -1e30f;
#pragma unroll
      for (int e = 0; e < NE; ++e) if (e != i0 && part[e] > b1) { b1 = part[e]; i1 = e; }
      idx[t * 2] = i0; idx[t * 2 + 1] = i1;
      atomicAdd(&usage[i0], 1u);
      unsigned pos = atomicAdd(&cnt[i0], 1u);
      perm[(size_t)i0 * T_TOK + pos] = t * 2;
      pos = atomicAdd(&cnt[i1], 1u);
      perm[(size_t)i1 * T_TOK + pos] = t * 2 + 1;
    }
  } else if (b < 3072) {
    // ---- cast x -> bf16 (8 elems / thread)
    int id = (b - 1024) * 256 + tid;
    const float4* src = (const float4*)x;
    float4 a = src[id * 2], v = src[id * 2 + 1];
    union { unsigned short u[8]; uint4 q; } o;
    o.u[0] = f2bf(a.x); o.u[1] = f2bf(a.y); o.u[2] = f2bf(a.z); o.u[3] = f2bf(a.w);
    o.u[4] = f2bf(v.x); o.u[5] = f2bf(v.y); o.u[6] = f2bf(v.z); o.u[7] = f2bf(v.w);
    ((uint4*)xb)[id] = o.q;
  } else {
    // ---- transpose W1 (R=D, C=H): 9 matrices x 512 tiles
    int l = b - 3072;
    int m = l >> 9, rem = l & 511;
    int c0 = (rem & 31) * 64, r0 = (rem >> 5) * 64;
    const float* src = (m < NE) ? W1 + (size_t)m * D_DIM * H_DIM : sW1;
    unsigned short* dst = (m < NE) ? W1t + (size_t)m * D_DIM * H_DIM : sW1t;
    transpose_tile<256>(src, dst, D_DIM, H_DIM, r0, c0, tid, tile);
  }
}

// ---------------------------------------------------------------- EM (512 threads) + KL loss
__device__ __forceinline__ void em_block512(const float* __restrict__ scores,
                                            const unsigned* __restrict__ usage,
                                            float* __restrict__ p_out, float* __restrict__ loss_out,
                                            int tid, char* smem) {
  float* p_sh = (float*)smem;       // 8
  float* cw = p_sh + 8;             // 8 waves * 8
  float* counts_sh = cw + 64;       // 8
  int wave = tid >> 6, lane = tid & 63;
  float s[8][NE];
#pragma unroll
  for (int rr = 0; rr < 8; ++rr) {
    int row = tid + rr * 512;
    const float4* sp = (const float4*)(scores + (size_t)row * NE);
    float4 a = sp[0], b = sp[1];
    s[rr][0] = a.x; s[rr][1] = a.y; s[rr][2] = a.z; s[rr][3] = a.w;
    s[rr][4] = b.x; s[rr][5] = b.y; s[rr][6] = b.z; s[rr][7] = b.w;
  }
  if (tid < NE) p_sh[tid] = 1.0f / NE;
  __syncthreads();
  for (int it = 0; it < 5; ++it) {
    float p[NE];
#pragma unroll
    for (int e = 0; e < NE; ++e) p[e] = p_sh[e];
    float c[NE];
#pragma unroll
    for (int e = 0; e < NE; ++e) c[e] = 0.f;
#pragma unroll
    for (int rr = 0; rr < 8; ++rr) {
      float denom = 0.f;
#pragma unroll
      for (int e = 0; e < NE; ++e) denom += s[rr][e] * p[e];
      float inv = 1.0f / (denom + EPSF);
#pragma unroll
      for (int e = 0; e < NE; ++e) c[e] += s[rr][e] * p[e] * inv;
    }
#pragma unroll
    for (int e = 0; e < NE; ++e) {
      float v = c[e];
      for (int off = 32; off; off >>= 1) v += __shfl_xor(v, off);
      c[e] = v;
    }
    if (lane == 0) {
#pragma unroll
      for (int e = 0; e < NE; ++e) cw[wave * 8 + e] = c[e];
    }
    __syncthreads();
    if (tid < NE) {
      float tot = 0.f;
#pragma unroll
      for (int w = 0; w < 8; ++w) tot += cw[w * 8 + tid];
      counts_sh[tid] = tot;
    }
    __syncthreads();
    if (tid < NE) {
      float total = 0.f;
#pragma unroll
      for (int e = 0; e < NE; ++e) total += counts_sh[e];
      p_sh[tid] = counts_sh[tid] / (total + EPSF);
    }
    __syncthreads();
  }
  if (tid < NE) p_out[tid] = p_sh[tid];
  if (tid == 0) {
    float actual[NE]; float norm = 0.f;
#pragma unroll
    for (int e = 0; e < NE; ++e) { actual[e] = (float)usage[e] / (float)T_TOK + EPSF; norm += actual[e]; }
    float u = 1.0f / NE;
    float kl = 0.f;
#pragma unroll
    for (int e = 0; e < NE; ++e) kl += u * (logf(u) - logf(actual[e] / norm));
    loss_out[0] = 0.1f * kl;
  }
}

// ---------------------------------------------------------------- 256x256 8-phase MFMA GEMM body
template <int KDIM, int NDIM, bool RELU, bool MODE1>
__device__ __forceinline__ void gemm_body(
    unsigned short* lds, int flat,
    const unsigned short* __restrict__ A, const unsigned short* __restrict__ WE,
    const unsigned short* __restrict__ WS, const float* __restrict__ biasE,
    const float* __restrict__ biasS, const int* __restrict__ perm,
    const unsigned* __restrict__ cnt, void* __restrict__ outp) {
  constexpr int BM = 256, BN = 256, BK = 64;
  constexpr int NT = NDIM / BN;
  constexpr int NKT = KDIM / BK;

  // ---- in-block plan from cnt[]
  int tc[9];
#pragma unroll
  for (int i = 0; i < NE; ++i) tc[i] = ((int)cnt[i] + 255) >> 8;
  tc[8] = T_TOK / 256;
  int nt = 0;
#pragma unroll
  for (int i = 0; i < 9; ++i) nt += tc[i];
  int W = nt * NT;
  int xcd = flat & 7, pos = flat >> 3;
  int q = W >> 3, r = W & 7;
  int mycount = q + (xcd < r ? 1 : 0);
  if (pos >= mycount) return;
  int mystart = xcd * q + (xcd < r ? xcd : r);
  int w = mystart + pos;
  int ti = w / NT;
  int n0 = (w % NT) * BN;
  int e = 0, mt = ti;
  while (mt >= tc[e]) { mt -= tc[e]; ++e; }
  int m0 = mt * BM;
  int cnt_e = (e == NE) ? T_TOK : (int)cnt[e];

  const unsigned short* Bmat = (e == NE) ? WS : WE + (size_t)e * KDIM * NDIM;
  const float* bias = (e == NE) ? biasS : biasE + (size_t)e * NDIM;

  int tid = threadIdx.x, wave = tid >> 6, lane = tid & 63;
  int wm = wave >> 1, wn = wave & 1;
  int frow = lane & 15, fks = lane >> 4;

  int srow = wave * 8 + (lane >> 3);
  int sslot = lane & 7;
  const unsigned short* aptr[2][2];
  const unsigned short* bptr[2][2];
#pragma unroll
  for (int h = 0; h < 2; ++h)
#pragma unroll
    for (int j = 0; j < 2; ++j) {
      int rr = h * 128 + j * 64 + srow;
      int colsw = (sslot ^ (rr & 7)) << 3;
      int ar = m0 + rr;
      if (ar > cnt_e - 1) ar = cnt_e - 1;
      int gar;
      if (e == NE) gar = MODE1 ? ar : (2 * T_TOK + ar);
      else { int v = perm[(size_t)e * T_TOK + ar]; gar = MODE1 ? (v >> 1) : v; }
      aptr[h][j] = A + (size_t)gar * KDIM + colsw;
      bptr[h][j] = Bmat + (size_t)(n0 + rr) * KDIM + colsw;
    }

  auto stA = [&](int t, int h) {
    int dbe = (t & 1) * 16384;
    int k0 = t * BK;
    gload_lds16(aptr[h][0] + k0, &lds[dbe + h * 8192 + wave * 512]);
    gload_lds16(aptr[h][1] + k0, &lds[dbe + h * 8192 + wave * 512 + 4096]);
  };
  auto stB = [&](int t, int h) {
    int dbe = (t & 1) * 16384;
    int k0 = t * BK;
    gload_lds16(bptr[h][0] + k0, &lds[32768 + dbe + h * 8192 + wave * 512]);
    gload_lds16(bptr[h][1] + k0, &lds[32768 + dbe + h * 8192 + wave * 512 + 4096]);
  };

  auto rdA = [&](int dbe, int ks, int m) -> bf16x8 {
    int rr = wm * 64 + m * 16 + frow;
    int slot = (ks * 4 + fks) ^ (rr & 7);
    return *(const bf16x8*)&lds[dbe + rr * 64 + slot * 8];
  };
  auto rdB = [&](int dbe, int ks, int bh, int jj) -> bf16x8 {
    int rr = bh * 128 + jj * 32 + wn * 16 + frow;
    int slot = (ks * 4 + fks) ^ (rr & 7);
    return *(const bf16x8*)&lds[32768 + dbe + rr * 64 + slot * 8];
  };

  f32x4 acc[4][8];
#pragma unroll
  for (int m = 0; m < 4; ++m)
#pragma unroll
    for (int nn = 0; nn < 8; ++nn) acc[m][nn] = (f32x4){0.f, 0.f, 0.f, 0.f};

  stA(0, 0); stA(0, 1);
  stB(0, 0); stB(0, 1);
  stA(1, 0); stA(1, 1);
  WAITV(6);
  BARR();

  for (int t = 0; t < NKT; ++t) {
    const int dbe = (t & 1) * 16384;
    bf16x8 a0[4], a1[4], bfr[4];

#pragma unroll
    for (int m = 0; m < 4; ++m) a0[m] = rdA(dbe, 0, m);
#pragma unroll
    for (int jj = 0; jj < 4; ++jj) bfr[jj] = rdB(dbe, 0, 0, jj);
    if (t + 1 < NKT) stB(t + 1, 0);
    BARR();
    __builtin_amdgcn_s_setprio(1);
#pragma unroll
    for (int m = 0; m < 4; ++m)
#pragma unroll
      for (int jj = 0; jj < 4; ++jj)
        acc[m][jj] = __builtin_amdgcn_mfma_f32_16x16x32_bf16(a0[m], bfr[jj], acc[m][jj], 0, 0, 0);
    __builtin_amdgcn_s_setprio(0);
    BARR();

#pragma unroll
    for (int m = 0; m < 4; ++m) a1[m] = rdA(dbe, 1, m);
#pragma unroll
    for (int jj = 0; jj < 4; ++jj) bfr[jj] = rdB(dbe, 1, 0, jj);
    if (t + 1 < NKT) stB(t + 1, 1);
    BARR();
    __builtin_amdgcn_s_setprio(1);
#pragma unroll
    for (int m = 0; m < 4; ++m)
#pragma unroll
      for (int jj = 0; jj < 4; ++jj)
        acc[m][jj] = __builtin_amdgcn_mfma_f32_16x16x32_bf16(a1[m], bfr[jj], acc[m][jj], 0, 0, 0);
    __builtin_amdgcn_s_setprio(0);
    if (t + 1 < NKT) { WAITV(8); } else { WAITV(0); }
    BARR();

#pragma unroll
    for (int jj = 0; jj < 4; ++jj) bfr[jj] = rdB(dbe, 0, 1, jj);
    if (t + 2 < NKT) stA(t + 2, 0);
    BARR();
    __builtin_amdgcn_s_setprio(1);
#pragma unroll
    for (int m = 0; m < 4; ++m)
#pragma unroll
      for (int jj = 0; jj < 4; ++jj)
        acc[m][4 + jj] = __builtin_amdgcn_mfma_f32_16x16x32_bf16(a0[m], bfr[jj], acc[m][4 + jj], 0, 0, 0);
    __builtin_amdgcn_s_setprio(0);
    BARR();

#pragma unroll
    for (int jj = 0; jj < 4; ++jj) bfr[jj] = rdB(dbe, 1, 1, jj);
    if (t + 2 < NKT) stA(t + 2, 1);
    BARR();
    __builtin_amdgcn_s_setprio(1);
#pragma unroll
    for (int m = 0; m < 4; ++m)
#pragma unroll
      for (int jj = 0; jj < 4; ++jj)
        acc[m][4 + jj] = __builtin_amdgcn_mfma_f32_16x16x32_bf16(a1[m], bfr[jj], acc[m][4 + jj], 0, 0, 0);
    __builtin_amdgcn_s_setprio(0);
    if (t + 1 < NKT) {
      if (t + 2 < NKT) { WAITV(6); } else { WAITV(2); }
    }
    BARR();
  }

#pragma unroll
  for (int m = 0; m < 4; ++m) {
#pragma unroll
    for (int qq = 0; qq < 4; ++qq) {
      int rt = wm * 64 + m * 16 + (lane >> 4) * 4 + qq;
      if (m0 + rt >= cnt_e) continue;
      int rr;
      if (e == NE) rr = 2 * T_TOK + m0 + rt;
      else rr = perm[(size_t)e * T_TOK + m0 + rt];
#pragma unroll
      for (int nn = 0; nn < 8; ++nn) {
        int col = n0 + (nn >> 2) * 128 + (nn & 3) * 32 + wn * 16 + (lane & 15);
        float val = acc[m][nn][qq] + bias[col];
        if (RELU) val = fmaxf(val, 0.f);
        if (MODE1)
          ((unsigned short*)outp)[(size_t)rr * NDIM + col] = f2bf(val);
        else
          ((float*)outp)[(size_t)rr * NDIM + col] = val;
      }
    }
  }
}

// ---------------------------------------------------------------- gemm1: GEMM | transpose W2 | em
// grid: [0,448) GEMM slots, [448, 448+4608) transpose W2-family, [5056] em+loss
__global__ __launch_bounds__(512, 2) void gemm1_kernel(
    const unsigned short* __restrict__ xb, const unsigned short* __restrict__ W1t,
    const unsigned short* __restrict__ sW1t, const float* __restrict__ b1,
    const float* __restrict__ sb1, const int* __restrict__ perm, const unsigned* __restrict__ cnt,
    unsigned short* __restrict__ Hbuf,
    const float* __restrict__ W2, const float* __restrict__ sW2,
    unsigned short* __restrict__ W2t, unsigned short* __restrict__ sW2t,
    const float* __restrict__ scores, const unsigned* __restrict__ usage,
    float* __restrict__ pbuf, float* __restrict__ loss_out) {
  __shared__ char smem[131072];
  int flat = blockIdx.x;
  if (flat < G1_GEMM) {
    gemm_body<D_DIM, H_DIM, true, true>((unsigned short*)smem, flat, xb, W1t, sW1t, b1, sb1,
                                        perm, cnt, (void*)Hbuf);
    return;
  }
  int l = flat - G1_GEMM;
  if (l < NTRANS) {
    // transpose W2 (R=H, C=D): 9 matrices x 512 tiles
    int m = l >> 9, rem = l & 511;
    int c0 = (rem & 15) * 64, r0 = (rem >> 4) * 64;
    const float* src = (m < NE) ? W2 + (size_t)m * H_DIM * D_DIM : sW2;
    unsigned short* dst = (m < NE) ? W2t + (size_t)m * H_DIM * D_DIM : sW2t;
    transpose_tile<512>(src, dst, H_DIM, D_DIM, r0, c0, threadIdx.x, (float*)smem);
    return;
  }
  em_block512(scores, usage, pbuf, loss_out, threadIdx.x, smem);
}

// ---------------------------------------------------------------- gemm2 (pure)
template <int KDIM, int NDIM, bool RELU, bool MODE1>
__global__ __launch_bounds__(512, 2) void gemm_kernel(
    const unsigned short* __restrict__ A, const unsigned short* __restrict__ WE,
    const unsigned short* __restrict__ WS, const float* __restrict__ biasE,
    const float* __restrict__ biasS, const int* __restrict__ perm,
    const unsigned* __restrict__ cnt, void* __restrict__ outp) {
  __shared__ char smem[131072];
  gemm_body<KDIM, NDIM, RELU, MODE1>((unsigned short*)smem, blockIdx.x, A, WE, WS, biasE, biasS,
                                     perm, cnt, outp);
}

// ---------------------------------------------------------------- combine
__global__ void combine_kernel(const float* __restrict__ ebuf, const float* __restrict__ scores,
                               const float* __restrict__ p, const int* __restrict__ idx,
                               float* __restrict__ out) {
  int gid = blockIdx.x * blockDim.x + threadIdx.x;
  int t = gid >> 8;
  int d4 = gid & 255;
  int e0 = idx[t * 2], e1 = idx[t * 2 + 1];
  float w0 = scores[(size_t)t * NE + e0] * p[e0];
  float w1 = scores[(size_t)t * NE + e1] * p[e1];
  const float4* r0 = (const float4*)(ebuf + (size_t)(t * 2) * D_DIM);
  const float4* r1 = (const float4*)(ebuf + (size_t)(t * 2 + 1) * D_DIM);
  const float4* rs = (const float4*)(ebuf + (size_t)(2 * T_TOK + t) * D_DIM);
  float4 a = r0[d4], b = r1[d4], c = rs[d4];
  float4 o;
  o.x = w0 * a.x + w1 * b.x + 0.1f * c.x;
  o.y = w0 * a.y + w1 * b.y + 0.1f * c.y;
  o.z = w0 * a.z + w1 * b.z + 0.1f * c.z;
  o.w = w0 * a.w + w1 * b.w + 0.1f * c.w;
  ((float4*)out)[gid] = o;
}

// ---------------------------------------------------------------- launch
extern "C" void kernel_launch(void* const* d_in, const int* in_sizes, int n_in,
                              void* d_out, int out_size, void* d_ws, size_t ws_size,
                              hipStream_t stream) {
  const float* x     = (const float*)d_in[0];
  const float* gW    = (const float*)d_in[1];
  const float* gb    = (const float*)d_in[2];
  const float* gtemp = (const float*)d_in[3];
  const float* W1    = (const float*)d_in[4];
  const float* b1    = (const float*)d_in[5];
  const float* W2    = (const float*)d_in[6];
  const float* b2    = (const float*)d_in[7];
  const float* sW1   = (const float*)d_in[8];
  const float* sb1   = (const float*)d_in[9];
  const float* sW2   = (const float*)d_in[10];
  const float* sb2   = (const float*)d_in[11];
  float* out = (float*)d_out;

  char* ws = (char*)d_ws;
  size_t off = 0;
  auto take = [&](size_t b) { char* ptr = ws + off; off += (b + 255) & ~(size_t)255; return ptr; };
  unsigned short* xb   = (unsigned short*)take((size_t)T_TOK * D_DIM * 2);
  unsigned short* W1t  = (unsigned short*)take((size_t)NE * H_DIM * D_DIM * 2);
  unsigned short* sW1t = (unsigned short*)take((size_t)H_DIM * D_DIM * 2);
  unsigned short* W2t  = (unsigned short*)take((size_t)NE * D_DIM * H_DIM * 2);
  unsigned short* sW2t = (unsigned short*)take((size_t)D_DIM * H_DIM * 2);
  unsigned short* Hbuf = (unsigned short*)take((size_t)3 * T_TOK * H_DIM * 2);
  float* ebuf          = (float*)take((size_t)3 * T_TOK * D_DIM * 4);
  float* scores        = (float*)take((size_t)T_TOK * NE * 4);
  int* idx             = (int*)take((size_t)T_TOK * 2 * 4);
  int* perm            = (int*)take((size_t)NE * T_TOK * 4);
  unsigned* cnt        = (unsigned*)take(256);
  unsigned* usage      = (unsigned*)take(256);
  float* pbuf          = (float*)take(256);
  (void)n_in; (void)in_sizes; (void)out_size; (void)ws_size;

  hipMemsetAsync(cnt, 0, 512, stream);  // cnt + usage (adjacent 256B blocks)
  prep_kernel<<<7680, 256, 0, stream>>>(x, gW, gb, gtemp, W1, sW1, W1t, sW1t, xb, scores, idx,
                                        usage, cnt, perm);
  gemm1_kernel<<<G1_GEMM + NTRANS + 1, 512, 0, stream>>>(
      xb, W1t, sW1t, b1, sb1, perm, cnt, Hbuf, W2, sW2, W2t, sW2t, scores, usage, pbuf,
      out + (size_t)T_TOK * D_DIM);
  gemm_kernel<H_DIM, D_DIM, false, false><<<G2_GEMM, 512, 0, stream>>>(
      Hbuf, W2t, sW2t, b2, sb2, perm, cnt, (void*)ebuf);
  combine_kernel<<<(T_TOK * D_DIM / 4) / 256, 256, 0, stream>>>(ebuf, scores, pbuf, idx, out);
}